// Round 2
// baseline (209897.046 us; speedup 1.0000x reference)
//
#include <hip/hip_runtime.h>
#include <hip/hip_bf16.h>
#include <hip/hip_cooperative_groups.h>

namespace cg = cooperative_groups;

#define BDIM 128
#define TDIM 1024
#define NIN  512
#define NH   1024
#define NOUT 256
#define NITER (TDIM + 2)

__device__ __forceinline__ float sigmoidf_(float x) { return 1.f / (1.f + __expf(-x)); }

struct ScanArgs {
    const float* u;
    const float* Wu[4];   // W_uf, W_ui, W_uo, W_uc   [512][1024]
    const float* Wh[4];   // W_hf, W_hi, W_ho, W_hc   [1024][1024]
    const float* WhyT;    // [256][1024] transposed W_hy
    const float* bg[4];   // b_f, b_i, b_o, b_c
    const float* by;
    float* hb0; float* hb1;   // [128][1024] ping-pong h
    float* lg0; float* lg1;   // [128][256]  ping-pong logits
    float* out;               // [128][1024][256]
};

// ---------------------------------------------------------------------------
// One scan iteration. 256 blocks x 512 threads.
// Gate GEMM: M=128 rows(batch), N=16 cols (4 h-cols x 4 gates), K=1536.
//   Thread slot: lane bits [0:2]=ks (K-split 8), [3:4]=gate, [5]=rg_lo;
//   wave w -> rg = w*2+rg_lo; rows rg*8..+8; micro 8x4; K-slice = 64 u-k
//   (ks*64..) + 128 h-k (ks*128..) -> uniform trip counts, no divergence.
//   Reduce over ks via 3x __shfl_xor (in-wave), ks==0 lanes write LDS.
// Y logits (y_{it-1} = h_it @ Why + by): col bx, 128 rows, K-split 4/thread.
// Softmax (y_{it-2}): blocks 0..127, wave 0, one batch-row each.
// ---------------------------------------------------------------------------
__device__ __forceinline__ void scan_iter(const ScanArgs& A, int it,
                                          float* pre, float* ylds)
{
    const int tid  = threadIdx.x;
    const int bx   = blockIdx.x;
    const int lane = tid & 63;
    const int wv   = tid >> 6;
    const int ks   = lane & 7;
    const int cgi  = (lane >> 3) & 3;
    const int rg   = wv * 2 + (lane >> 5);
    const int c0   = bx * 4;

    const float* hcur = (it & 1) ? A.hb1 : A.hb0;
    float* hnext      = (it & 1) ? A.hb0 : A.hb1;
    float* Lw         = (it & 1) ? A.lg1 : A.lg0;
    const float* Lr   = (it & 1) ? A.lg0 : A.lg1;

    // ---------------- softmax of logits from step it-2 ----------------
    if (it >= 2 && bx < BDIM && tid < 64) {
        const int r = bx, t = it - 2;
        float4 v = *(const float4*)(Lr + (size_t)r * NOUT + tid * 4);
        float mx = fmaxf(fmaxf(v.x, v.y), fmaxf(v.z, v.w));
#pragma unroll
        for (int d = 1; d < 64; d <<= 1) mx = fmaxf(mx, __shfl_xor(mx, d));
        v.x = __expf(v.x - mx); v.y = __expf(v.y - mx);
        v.z = __expf(v.z - mx); v.w = __expf(v.w - mx);
        float s = v.x + v.y + v.z + v.w;
#pragma unroll
        for (int d = 1; d < 64; d <<= 1) s += __shfl_xor(s, d);
        const float inv = 1.f / s;
        v.x *= inv; v.y *= inv; v.z *= inv; v.w *= inv;
        *(float4*)(A.out + ((size_t)r * TDIM + t) * NOUT + tid * 4) = v;
    }

    // ---------------- gate pre-activation GEMM ----------------
    if (it < TDIM) {
        const int t  = it;
        const int r0 = rg * 8;
        const float* Wu = A.Wu[cgi] + c0;
        const float* Wh = A.Wh[cgi] + c0;
        float acc[8][4];
#pragma unroll
        for (int i = 0; i < 8; ++i)
#pragma unroll
            for (int j = 0; j < 4; ++j) acc[i][j] = 0.f;

        {   // u-part: k in [ks*64, ks*64+64)
            const int kb = ks * 64;
#pragma unroll 2
            for (int q = 0; q < 16; ++q) {
                const int k = kb + q * 4;
                const float4 w0 = *(const float4*)(Wu + (size_t)(k + 0) * NH);
                const float4 w1 = *(const float4*)(Wu + (size_t)(k + 1) * NH);
                const float4 w2 = *(const float4*)(Wu + (size_t)(k + 2) * NH);
                const float4 w3 = *(const float4*)(Wu + (size_t)(k + 3) * NH);
#pragma unroll
                for (int i = 0; i < 8; ++i) {
                    const float4 a = *(const float4*)(A.u +
                        ((size_t)(r0 + i) * TDIM + t) * NIN + k);
                    acc[i][0] = fmaf(a.x, w0.x, acc[i][0]);
                    acc[i][1] = fmaf(a.x, w0.y, acc[i][1]);
                    acc[i][2] = fmaf(a.x, w0.z, acc[i][2]);
                    acc[i][3] = fmaf(a.x, w0.w, acc[i][3]);
                    acc[i][0] = fmaf(a.y, w1.x, acc[i][0]);
                    acc[i][1] = fmaf(a.y, w1.y, acc[i][1]);
                    acc[i][2] = fmaf(a.y, w1.z, acc[i][2]);
                    acc[i][3] = fmaf(a.y, w1.w, acc[i][3]);
                    acc[i][0] = fmaf(a.z, w2.x, acc[i][0]);
                    acc[i][1] = fmaf(a.z, w2.y, acc[i][1]);
                    acc[i][2] = fmaf(a.z, w2.z, acc[i][2]);
                    acc[i][3] = fmaf(a.z, w2.w, acc[i][3]);
                    acc[i][0] = fmaf(a.w, w3.x, acc[i][0]);
                    acc[i][1] = fmaf(a.w, w3.y, acc[i][1]);
                    acc[i][2] = fmaf(a.w, w3.z, acc[i][2]);
                    acc[i][3] = fmaf(a.w, w3.w, acc[i][3]);
                }
            }
        }
        {   // h-part: k in [ks*128, ks*128+128)
            const int kb = ks * 128;
#pragma unroll 2
            for (int q = 0; q < 32; ++q) {
                const int k = kb + q * 4;
                const float4 w0 = *(const float4*)(Wh + (size_t)(k + 0) * NH);
                const float4 w1 = *(const float4*)(Wh + (size_t)(k + 1) * NH);
                const float4 w2 = *(const float4*)(Wh + (size_t)(k + 2) * NH);
                const float4 w3 = *(const float4*)(Wh + (size_t)(k + 3) * NH);
#pragma unroll
                for (int i = 0; i < 8; ++i) {
                    const float4 a = *(const float4*)(hcur +
                        (size_t)(r0 + i) * NH + k);
                    acc[i][0] = fmaf(a.x, w0.x, acc[i][0]);
                    acc[i][1] = fmaf(a.x, w0.y, acc[i][1]);
                    acc[i][2] = fmaf(a.x, w0.z, acc[i][2]);
                    acc[i][3] = fmaf(a.x, w0.w, acc[i][3]);
                    acc[i][0] = fmaf(a.y, w1.x, acc[i][0]);
                    acc[i][1] = fmaf(a.y, w1.y, acc[i][1]);
                    acc[i][2] = fmaf(a.y, w1.z, acc[i][2]);
                    acc[i][3] = fmaf(a.y, w1.w, acc[i][3]);
                    acc[i][0] = fmaf(a.z, w2.x, acc[i][0]);
                    acc[i][1] = fmaf(a.z, w2.y, acc[i][1]);
                    acc[i][2] = fmaf(a.z, w2.z, acc[i][2]);
                    acc[i][3] = fmaf(a.z, w2.w, acc[i][3]);
                    acc[i][0] = fmaf(a.w, w3.x, acc[i][0]);
                    acc[i][1] = fmaf(a.w, w3.y, acc[i][1]);
                    acc[i][2] = fmaf(a.w, w3.z, acc[i][2]);
                    acc[i][3] = fmaf(a.w, w3.w, acc[i][3]);
                }
            }
        }
        // reduce over ks (lane bits 0..2) via in-wave butterfly
#pragma unroll
        for (int i = 0; i < 8; ++i)
#pragma unroll
            for (int j = 0; j < 4; ++j) {
                float v = acc[i][j];
                v += __shfl_xor(v, 1);
                v += __shfl_xor(v, 2);
                v += __shfl_xor(v, 4);
                acc[i][j] = v;
            }
        if (ks == 0) {
#pragma unroll
            for (int i = 0; i < 8; ++i)
                *(float4*)&pre[(size_t)(r0 + i) * 20 + cgi * 4] =
                    make_float4(acc[i][0], acc[i][1], acc[i][2], acc[i][3]);
        }
    }

    // ---------------- Y logits partials (y_{it-1} from h_it) ----------------
    if (it >= 1 && it <= TDIM) {
        const int yrow = tid >> 2;
        const int kb   = (tid & 3) * 256;
        const float* hp = hcur + (size_t)yrow * NH;
        const float* wp = A.WhyT + (size_t)bx * NH;
        float ya = 0.f;
#pragma unroll 4
        for (int q = 0; q < 64; ++q) {
            const int k = kb + q * 4;
            const float4 h4 = *(const float4*)(hp + k);
            const float4 w4 = *(const float4*)(wp + k);
            ya = fmaf(h4.x, w4.x, ya);
            ya = fmaf(h4.y, w4.y, ya);
            ya = fmaf(h4.z, w4.z, ya);
            ya = fmaf(h4.w, w4.w, ya);
        }
        ylds[tid] = ya;
    }

    __syncthreads();

    // ---------------- gate combine -> h_{it+1} ----------------
    if (it < TDIM) {
        const int row = tid >> 2, hc = tid & 3;
        const float* pr = pre + (size_t)row * 20 + hc;
        const float gf = sigmoidf_(pr[0]  + A.bg[0][c0 + hc]);
        const float gi = sigmoidf_(pr[4]  + A.bg[1][c0 + hc]);
        const float go = sigmoidf_(pr[8]  + A.bg[2][c0 + hc]);
        const float ct = tanhf    (pr[12] + A.bg[3][c0 + hc]);
        const float ho = hcur[(size_t)row * NH + c0 + hc];
        // faithful to source: c_new = f*h + i*c_tilde  (uses h, not c)
        const float cn = gf * ho + gi * ct;
        hnext[(size_t)row * NH + c0 + hc] = go * tanhf(cn);
    }

    // ---------------- Y reduce + logit write ----------------
    if (it >= 1 && it <= TDIM && tid < BDIM) {
        const float4 yv = *(const float4*)&ylds[tid * 4];
        Lw[(size_t)tid * NOUT + bx] = yv.x + yv.y + yv.z + yv.w + A.by[bx];
    }
}

__global__ __launch_bounds__(512, 2) void scan_coop(ScanArgs A)
{
    __shared__ float pre[BDIM * 20];
    __shared__ float ylds[512];
    cg::grid_group grid = cg::this_grid();
    for (int it = 0; it < NITER; ++it) {
        scan_iter(A, it, pre, ylds);
        grid.sync();
    }
}

// Fallback: one launch per iteration (kernel boundary = global sync)
__global__ __launch_bounds__(512, 2) void scan_step(ScanArgs A, int it)
{
    __shared__ float pre[BDIM * 20];
    __shared__ float ylds[512];
    scan_iter(A, it, pre, ylds);
}

// ---------------------------------------------------------------------------
__global__ void transpose_why(const float* __restrict__ Why,
                              float* __restrict__ WhyT)
{
    __shared__ float tile[32][33];
    const int k0 = blockIdx.x * 32;
    const int n0 = blockIdx.y * 32;
    const int tx = threadIdx.x, ty = threadIdx.y;
#pragma unroll
    for (int r = 0; r < 4; ++r)
        tile[ty * 4 + r][tx] = Why[(size_t)(k0 + ty * 4 + r) * NOUT + n0 + tx];
    __syncthreads();
#pragma unroll
    for (int r = 0; r < 4; ++r)
        WhyT[(size_t)(n0 + ty * 4 + r) * NH + k0 + tx] = tile[tx][ty * 4 + r];
}

__global__ void init_h(const float* __restrict__ h0, float* __restrict__ hb)
{
    const int i = blockIdx.x * 256 + threadIdx.x;
    hb[i] = h0[i & (NH - 1)];
}

// ---------------------------------------------------------------------------
extern "C" void kernel_launch(void* const* d_in, const int* in_sizes, int n_in,
                              void* d_out, int out_size, void* d_ws, size_t ws_size,
                              hipStream_t stream)
{
    (void)in_sizes; (void)n_in; (void)out_size; (void)ws_size;
    const float* u   = (const float*)d_in[0];
    const float* Wuf = (const float*)d_in[1];
    const float* Wui = (const float*)d_in[2];
    const float* Wuo = (const float*)d_in[3];
    const float* Wuc = (const float*)d_in[4];
    const float* Whf = (const float*)d_in[5];
    const float* Whi = (const float*)d_in[6];
    const float* Who = (const float*)d_in[7];
    const float* Whc = (const float*)d_in[8];
    const float* Why = (const float*)d_in[9];
    const float* bf  = (const float*)d_in[10];
    const float* bi  = (const float*)d_in[11];
    const float* bo  = (const float*)d_in[12];
    const float* bc  = (const float*)d_in[13];
    const float* by  = (const float*)d_in[14];
    const float* h0  = (const float*)d_in[15];
    float* out = (float*)d_out;

    // workspace layout (total ~2.25 MB — safe for any plausible ws_size)
    float* WhyT = (float*)d_ws;                     // 256*1024
    float* hb0  = WhyT + (size_t)NOUT * NH;         // 128*1024
    float* hb1  = hb0  + (size_t)BDIM * NH;
    float* lg0  = hb1  + (size_t)BDIM * NH;         // 128*256
    float* lg1  = lg0  + (size_t)BDIM * NOUT;

    transpose_why<<<dim3(NH / 32, NOUT / 32), dim3(32, 8), 0, stream>>>(Why, WhyT);
    init_h<<<dim3(BDIM * NH / 256), dim3(256), 0, stream>>>(h0, hb0);

    ScanArgs A;
    A.u = u;
    A.Wu[0] = Wuf; A.Wu[1] = Wui; A.Wu[2] = Wuo; A.Wu[3] = Wuc;
    A.Wh[0] = Whf; A.Wh[1] = Whi; A.Wh[2] = Who; A.Wh[3] = Whc;
    A.WhyT = WhyT;
    A.bg[0] = bf; A.bg[1] = bi; A.bg[2] = bo; A.bg[3] = bc;
    A.by = by;
    A.hb0 = hb0; A.hb1 = hb1; A.lg0 = lg0; A.lg1 = lg1;
    A.out = out;

    void* args[] = { (void*)&A };
    hipError_t e = hipLaunchCooperativeKernel((void*)scan_coop, dim3(256),
                                              dim3(512), args, 0, stream);
    if (e != hipSuccess) {
        // fallback: per-iteration launches; kernel boundary provides the sync
        for (int it = 0; it < NITER; ++it)
            scan_step<<<dim3(256), dim3(512), 0, stream>>>(A, it);
    }
}